// Round 1
// baseline (1525.596 us; speedup 1.0000x reference)
//
#include <hip/hip_runtime.h>

#define H 128

typedef __bf16 bf16_t;
typedef bf16_t bf16x8 __attribute__((ext_vector_type(8)));
typedef bf16_t bf16x4 __attribute__((ext_vector_type(4)));
typedef float f32x4 __attribute__((ext_vector_type(4)));

// ---- f32 -> bf16 conversion (vectorized, total must be %4==0) ----
__global__ void k_conv4(const float* __restrict__ in, bf16_t* __restrict__ out, int total) {
    int idx = (blockIdx.x * blockDim.x + threadIdx.x) * 4;
    if (idx < total) {
        float4 v = *(const float4*)(in + idx);
        bf16x4 o;
        o[0] = (bf16_t)v.x; o[1] = (bf16_t)v.y; o[2] = (bf16_t)v.z; o[3] = (bf16_t)v.w;
        *(bf16x4*)(out + idx) = o;
    }
}

// ---- degree histogram ----
__global__ void k_hist(const int* __restrict__ col, int* __restrict__ deg, int E) {
    int e = blockIdx.x * blockDim.x + threadIdx.x;
    if (e < E) atomicAdd(deg + col[e], 1);
}

// ---- per-1024-chunk partial sums of deg ----
__global__ void k_partial(const int* __restrict__ deg, int* __restrict__ partial, int NN) {
    __shared__ int s[256];
    int base = blockIdx.x * 1024 + threadIdx.x * 4;
    int t = 0;
#pragma unroll
    for (int j = 0; j < 4; ++j) { int n = base + j; if (n < NN) t += deg[n]; }
    s[threadIdx.x] = t;
    __syncthreads();
    for (int off = 128; off > 0; off >>= 1) {
        if (threadIdx.x < off) s[threadIdx.x] += s[threadIdx.x + off];
        __syncthreads();
    }
    if (threadIdx.x == 0) partial[blockIdx.x] = s[0];
}

// ---- serial exclusive scan of the (tiny) partial array ----
__global__ void k_scan_partial(int* __restrict__ partial, int NB) {
    if (blockIdx.x == 0 && threadIdx.x == 0) {
        int run = 0;
        for (int i = 0; i < NB; ++i) { int t = partial[i]; partial[i] = run; run += t; }
    }
}

// ---- per-chunk exclusive scan -> CSC offsets, cursor copy, inv-degree ----
__global__ void k_offsets(const int* __restrict__ deg, const int* __restrict__ partial,
                          int* __restrict__ offs, int* __restrict__ cursor,
                          float* __restrict__ invdeg, int NN, int E) {
    __shared__ int s[256];
    int tid = threadIdx.x;
    int base = blockIdx.x * 1024 + tid * 4;
    int d[4]; int tsum = 0;
#pragma unroll
    for (int j = 0; j < 4; ++j) { int n = base + j; d[j] = (n < NN) ? deg[n] : 0; tsum += d[j]; }
    s[tid] = tsum;
    __syncthreads();
    for (int off = 1; off < 256; off <<= 1) {
        int v = (tid >= off) ? s[tid - off] : 0;
        __syncthreads();
        s[tid] += v;
        __syncthreads();
    }
    int run = partial[blockIdx.x] + s[tid] - tsum;  // exclusive base for this thread
#pragma unroll
    for (int j = 0; j < 4; ++j) {
        int n = base + j;
        if (n < NN) {
            offs[n] = run;
            cursor[n] = run;
            int dd = d[j] > 1 ? d[j] : 1;
            invdeg[n] = 1.0f / (float)dd;
            run += d[j];
        }
    }
    if (blockIdx.x == 0 && tid == 0) offs[NN] = E;
}

// ---- bucket edges by destination ----
__global__ void k_scatter(const int* __restrict__ row, const int* __restrict__ col,
                          int* __restrict__ cursor, int* __restrict__ srcid, int E) {
    int e = blockIdx.x * blockDim.x + threadIdx.x;
    if (e < E) {
        int pos = atomicAdd(cursor + col[e], 1);
        srcid[pos] = row[e];
    }
}

// ---- per-node segmented mean-aggregate (atomic-free), bf16 in/out ----
__global__ void k_agg(const bf16_t* __restrict__ xbf, const int* __restrict__ offs,
                      const int* __restrict__ srcid, const float* __restrict__ invdeg,
                      bf16_t* __restrict__ msg, int NN) {
    int n = blockIdx.x;          // one node per block
    int f = threadIdx.x;         // 128 threads = feature lane
    int e0 = offs[n], e1 = offs[n + 1];
    float sum = 0.f;
    for (int e = e0; e < e1; ++e) {
        int s = srcid[e];
        sum += (float)xbf[(size_t)s * H + f];
    }
    msg[(size_t)n * H + f] = (bf16_t)(sum * invdeg[n]);
}

// ---- fused MFMA GEMM: out = xold + relu(msg @ W^T + bias); also refresh bf16 mirror ----
__global__ __launch_bounds__(256) void k_gemm(const bf16_t* __restrict__ msg, const bf16_t* __restrict__ wbf,
                                              const float* __restrict__ bias, const float* __restrict__ xold,
                                              float* __restrict__ xnew, bf16_t* __restrict__ xbf, int NN) {
    const int tid = threadIdx.x;
    const int wid = tid >> 6;          // wave 0..3
    const int lane = tid & 63;
    const int lr = lane & 15;          // A row / B col / D col
    const int lg = lane >> 4;          // k-group / D row-group
    const int m0 = blockIdx.x * 64 + wid * 16;   // wave's 16 output rows

    f32x4 acc[8] = {};
    int ar = m0 + lr;
    if (ar >= NN) ar = NN - 1;         // clamp: garbage rows only feed unstored outputs
    const bf16_t* arow = msg + (size_t)ar * H;

#pragma unroll
    for (int kk = 0; kk < 4; ++kk) {
        bf16x8 a = *(const bf16x8*)(arow + kk * 32 + lg * 8);
#pragma unroll
        for (int c = 0; c < 8; ++c) {
            bf16x8 b = *(const bf16x8*)(wbf + (size_t)(c * 16 + lr) * H + kk * 32 + lg * 8);
            acc[c] = __builtin_amdgcn_mfma_f32_16x16x32_bf16(a, b, acc[c], 0, 0, 0);
        }
    }

#pragma unroll
    for (int c = 0; c < 8; ++c) {
        int colN = c * 16 + lr;
        float bv = bias[colN];
#pragma unroll
        for (int j = 0; j < 4; ++j) {
            int r = m0 + lg * 4 + j;
            if (r < NN) {
                float v = acc[c][j] + bv;
                v = fmaxf(v, 0.f);
                size_t o = (size_t)r * H + colN;
                float xn = xold[o] + v;
                xnew[o] = xn;
                xbf[o] = (bf16_t)xn;
            }
        }
    }
}

extern "C" void kernel_launch(void* const* d_in, const int* in_sizes, int n_in,
                              void* d_out, int out_size, void* d_ws, size_t ws_size,
                              hipStream_t stream) {
    const float* x_in  = (const float*)d_in[0];
    const int*   erow  = (const int*)d_in[1];
    const float* W     = (const float*)d_in[2];
    const float* bias  = (const float*)d_in[3];

    const int NN = in_sizes[0] / H;      // 100000
    const int E  = in_sizes[1] / 2;      // 1600000
    const int* ecol = erow + E;

    float* xout = (float*)d_out;

    // workspace carve (256B aligned regions)
    char* p = (char*)d_ws;
    auto carve = [&](size_t bytes) -> char* {
        char* r = p;
        p += (bytes + 255) & ~(size_t)255;
        return r;
    };
    bf16_t* xbf    = (bf16_t*)carve((size_t)NN * H * 2);
    bf16_t* msg    = (bf16_t*)carve((size_t)NN * H * 2);
    bf16_t* wbf    = (bf16_t*)carve((size_t)H * H * 2);
    int*    deg    = (int*)carve((size_t)NN * 4);
    int*    offs   = (int*)carve((size_t)(NN + 1) * 4);
    int*    cursor = (int*)carve((size_t)NN * 4);
    float*  invdeg = (float*)carve((size_t)NN * 4);
    int*    srcid  = (int*)carve((size_t)E * 4);
    int*    partial= (int*)carve((size_t)((NN + 1023) / 1024) * 4);

    const int NB = (NN + 1023) / 1024;

    // ---- one-time setup per call ----
    k_conv4<<<(NN * H / 4 + 255) / 256, 256, 0, stream>>>(x_in, xbf, NN * H);
    k_conv4<<<(H * H / 4 + 255) / 256, 256, 0, stream>>>(W, wbf, H * H);
    hipMemsetAsync(deg, 0, (size_t)NN * 4, stream);
    k_hist<<<(E + 255) / 256, 256, 0, stream>>>(ecol, deg, E);
    k_partial<<<NB, 256, 0, stream>>>(deg, partial, NN);
    k_scan_partial<<<1, 64, 0, stream>>>(partial, NB);
    k_offsets<<<NB, 256, 0, stream>>>(deg, partial, offs, cursor, invdeg, NN, E);
    k_scatter<<<(E + 255) / 256, 256, 0, stream>>>(erow, ecol, cursor, srcid, E);

    // ---- 6 message-passing iterations ----
    for (int it = 0; it < 6; ++it) {
        k_agg<<<NN, 128, 0, stream>>>(xbf, offs, srcid, invdeg, msg, NN);
        const float* xo = (it == 0) ? x_in : (const float*)xout;
        k_gemm<<<(NN + 63) / 64, 256, 0, stream>>>(msg, wbf, bias, xo, xout, xbf, NN);
    }
}

// Round 2
// 933.741 us; speedup vs baseline: 1.6339x; 1.6339x over previous
//
#include <hip/hip_runtime.h>

#define H 128

typedef __bf16 bf16_t;
typedef bf16_t bf16x8 __attribute__((ext_vector_type(8)));
typedef bf16_t bf16x4 __attribute__((ext_vector_type(4)));
typedef float f32x4 __attribute__((ext_vector_type(4)));

// ---- f32 -> bf16 conversion (vectorized, total must be %4==0) ----
__global__ void k_conv4(const float* __restrict__ in, bf16_t* __restrict__ out, int total) {
    int idx = (blockIdx.x * blockDim.x + threadIdx.x) * 4;
    if (idx < total) {
        float4 v = *(const float4*)(in + idx);
        bf16x4 o;
        o[0] = (bf16_t)v.x; o[1] = (bf16_t)v.y; o[2] = (bf16_t)v.z; o[3] = (bf16_t)v.w;
        *(bf16x4*)(out + idx) = o;
    }
}

// ---- degree histogram ----
__global__ void k_hist(const int* __restrict__ col, int* __restrict__ deg, int E) {
    int e = blockIdx.x * blockDim.x + threadIdx.x;
    if (e < E) atomicAdd(deg + col[e], 1);
}

// ---- per-1024-chunk partial sums of deg ----
__global__ void k_partial(const int* __restrict__ deg, int* __restrict__ partial, int NN) {
    __shared__ int s[256];
    int base = blockIdx.x * 1024 + threadIdx.x * 4;
    int t = 0;
#pragma unroll
    for (int j = 0; j < 4; ++j) { int n = base + j; if (n < NN) t += deg[n]; }
    s[threadIdx.x] = t;
    __syncthreads();
    for (int off = 128; off > 0; off >>= 1) {
        if (threadIdx.x < off) s[threadIdx.x] += s[threadIdx.x + off];
        __syncthreads();
    }
    if (threadIdx.x == 0) partial[blockIdx.x] = s[0];
}

// ---- serial exclusive scan of the (tiny) partial array ----
__global__ void k_scan_partial(int* __restrict__ partial, int NB) {
    if (blockIdx.x == 0 && threadIdx.x == 0) {
        int run = 0;
        for (int i = 0; i < NB; ++i) { int t = partial[i]; partial[i] = run; run += t; }
    }
}

// ---- per-chunk exclusive scan -> CSC offsets, cursor copy, inv-degree ----
__global__ void k_offsets(const int* __restrict__ deg, const int* __restrict__ partial,
                          int* __restrict__ offs, int* __restrict__ cursor,
                          float* __restrict__ invdeg, int NN, int E) {
    __shared__ int s[256];
    int tid = threadIdx.x;
    int base = blockIdx.x * 1024 + tid * 4;
    int d[4]; int tsum = 0;
#pragma unroll
    for (int j = 0; j < 4; ++j) { int n = base + j; d[j] = (n < NN) ? deg[n] : 0; tsum += d[j]; }
    s[tid] = tsum;
    __syncthreads();
    for (int off = 1; off < 256; off <<= 1) {
        int v = (tid >= off) ? s[tid - off] : 0;
        __syncthreads();
        s[tid] += v;
        __syncthreads();
    }
    int run = partial[blockIdx.x] + s[tid] - tsum;  // exclusive base for this thread
#pragma unroll
    for (int j = 0; j < 4; ++j) {
        int n = base + j;
        if (n < NN) {
            offs[n] = run;
            cursor[n] = run;
            int dd = d[j] > 1 ? d[j] : 1;
            invdeg[n] = 1.0f / (float)dd;
            run += d[j];
        }
    }
    if (blockIdx.x == 0 && tid == 0) offs[NN] = E;
}

// ---- bucket edges by destination ----
__global__ void k_scatter(const int* __restrict__ row, const int* __restrict__ col,
                          int* __restrict__ cursor, int* __restrict__ srcid, int E) {
    int e = blockIdx.x * blockDim.x + threadIdx.x;
    if (e < E) {
        int pos = atomicAdd(cursor + col[e], 1);
        srcid[pos] = row[e];
    }
}

// ---- per-node segmented mean-aggregate (atomic-free), bf16 in/out ----
// One node per WAVE. Quarter-wave (16 lanes) per edge slot -> 4 edges
// gathered concurrently; each lane loads bf16x8 (16B). 2-edge unroll gives
// 2 independent gathers in flight per lane. Cross-quarter reduce via
// shfl_xor(16/32), quarter 0 writes the 256B row.
__global__ __launch_bounds__(256) void k_agg(const bf16_t* __restrict__ xbf, const int* __restrict__ offs,
                                             const int* __restrict__ srcid, const float* __restrict__ invdeg,
                                             bf16_t* __restrict__ msg, int NN) {
    const int wid  = threadIdx.x >> 6;
    const int lane = threadIdx.x & 63;
    const int n    = blockIdx.x * 4 + wid;
    if (n >= NN) return;
    const int qid = lane >> 4;     // edge slot 0..3
    const int f   = lane & 15;     // feature group: 8f .. 8f+7

    const int e0 = offs[n], e1 = offs[n + 1];

    float acc[8] = {0.f, 0.f, 0.f, 0.f, 0.f, 0.f, 0.f, 0.f};

    int e = e0 + qid;
    // 2-edge unrolled main loop: two independent row gathers in flight
    while (e + 4 < e1) {
        int s0 = srcid[e];
        int s1 = srcid[e + 4];
        bf16x8 v0 = *(const bf16x8*)(xbf + (size_t)s0 * H + f * 8);
        bf16x8 v1 = *(const bf16x8*)(xbf + (size_t)s1 * H + f * 8);
#pragma unroll
        for (int j = 0; j < 8; ++j) acc[j] += (float)v0[j] + (float)v1[j];
        e += 8;
    }
    if (e < e1) {
        int s0 = srcid[e];
        bf16x8 v0 = *(const bf16x8*)(xbf + (size_t)s0 * H + f * 8);
#pragma unroll
        for (int j = 0; j < 8; ++j) acc[j] += (float)v0[j];
    }

    // reduce across the 4 quarter-waves (feature groups align across quarters)
#pragma unroll
    for (int j = 0; j < 8; ++j) {
        acc[j] += __shfl_xor(acc[j], 16);
        acc[j] += __shfl_xor(acc[j], 32);
    }

    if (qid == 0) {
        float inv = invdeg[n];
        bf16x8 o;
#pragma unroll
        for (int j = 0; j < 8; ++j) o[j] = (bf16_t)(acc[j] * inv);
        *(bf16x8*)(msg + (size_t)n * H + f * 8) = o;
    }
}

// ---- fused MFMA GEMM: out = xold + relu(msg @ W^T + bias); also refresh bf16 mirror ----
__global__ __launch_bounds__(256) void k_gemm(const bf16_t* __restrict__ msg, const bf16_t* __restrict__ wbf,
                                              const float* __restrict__ bias, const float* __restrict__ xold,
                                              float* __restrict__ xnew, bf16_t* __restrict__ xbf, int NN) {
    const int tid = threadIdx.x;
    const int wid = tid >> 6;          // wave 0..3
    const int lane = tid & 63;
    const int lr = lane & 15;          // A row / B col / D col
    const int lg = lane >> 4;          // k-group / D row-group
    const int m0 = blockIdx.x * 64 + wid * 16;   // wave's 16 output rows

    f32x4 acc[8] = {};
    int ar = m0 + lr;
    if (ar >= NN) ar = NN - 1;         // clamp: garbage rows only feed unstored outputs
    const bf16_t* arow = msg + (size_t)ar * H;

#pragma unroll
    for (int kk = 0; kk < 4; ++kk) {
        bf16x8 a = *(const bf16x8*)(arow + kk * 32 + lg * 8);
#pragma unroll
        for (int c = 0; c < 8; ++c) {
            bf16x8 b = *(const bf16x8*)(wbf + (size_t)(c * 16 + lr) * H + kk * 32 + lg * 8);
            acc[c] = __builtin_amdgcn_mfma_f32_16x16x32_bf16(a, b, acc[c], 0, 0, 0);
        }
    }

#pragma unroll
    for (int c = 0; c < 8; ++c) {
        int colN = c * 16 + lr;
        float bv = bias[colN];
#pragma unroll
        for (int j = 0; j < 4; ++j) {
            int r = m0 + lg * 4 + j;
            if (r < NN) {
                float v = acc[c][j] + bv;
                v = fmaxf(v, 0.f);
                size_t o = (size_t)r * H + colN;
                float xn = xold[o] + v;
                xnew[o] = xn;
                xbf[o] = (bf16_t)xn;
            }
        }
    }
}

extern "C" void kernel_launch(void* const* d_in, const int* in_sizes, int n_in,
                              void* d_out, int out_size, void* d_ws, size_t ws_size,
                              hipStream_t stream) {
    const float* x_in  = (const float*)d_in[0];
    const int*   erow  = (const int*)d_in[1];
    const float* W     = (const float*)d_in[2];
    const float* bias  = (const float*)d_in[3];

    const int NN = in_sizes[0] / H;      // 100000
    const int E  = in_sizes[1] / 2;      // 1600000
    const int* ecol = erow + E;

    float* xout = (float*)d_out;

    // workspace carve (256B aligned regions)
    char* p = (char*)d_ws;
    auto carve = [&](size_t bytes) -> char* {
        char* r = p;
        p += (bytes + 255) & ~(size_t)255;
        return r;
    };
    bf16_t* xbf    = (bf16_t*)carve((size_t)NN * H * 2);
    bf16_t* msg    = (bf16_t*)carve((size_t)NN * H * 2);
    bf16_t* wbf    = (bf16_t*)carve((size_t)H * H * 2);
    int*    deg    = (int*)carve((size_t)NN * 4);
    int*    offs   = (int*)carve((size_t)(NN + 1) * 4);
    int*    cursor = (int*)carve((size_t)NN * 4);
    float*  invdeg = (float*)carve((size_t)NN * 4);
    int*    srcid  = (int*)carve((size_t)E * 4);
    int*    partial= (int*)carve((size_t)((NN + 1023) / 1024) * 4);

    const int NB = (NN + 1023) / 1024;

    // ---- one-time setup per call ----
    k_conv4<<<(NN * H / 4 + 255) / 256, 256, 0, stream>>>(x_in, xbf, NN * H);
    k_conv4<<<(H * H / 4 + 255) / 256, 256, 0, stream>>>(W, wbf, H * H);
    hipMemsetAsync(deg, 0, (size_t)NN * 4, stream);
    k_hist<<<(E + 255) / 256, 256, 0, stream>>>(ecol, deg, E);
    k_partial<<<NB, 256, 0, stream>>>(deg, partial, NN);
    k_scan_partial<<<1, 64, 0, stream>>>(partial, NB);
    k_offsets<<<NB, 256, 0, stream>>>(deg, partial, offs, cursor, invdeg, NN, E);
    k_scatter<<<(E + 255) / 256, 256, 0, stream>>>(erow, ecol, cursor, srcid, E);

    // ---- 6 message-passing iterations ----
    for (int it = 0; it < 6; ++it) {
        k_agg<<<(NN + 3) / 4, 256, 0, stream>>>(xbf, offs, srcid, invdeg, msg, NN);
        const float* xo = (it == 0) ? x_in : (const float*)xout;
        k_gemm<<<(NN + 63) / 64, 256, 0, stream>>>(msg, wbf, bias, xo, xout, xbf, NN);
    }
}

// Round 3
// 921.290 us; speedup vs baseline: 1.6559x; 1.0135x over previous
//
#include <hip/hip_runtime.h>

#define H 128

typedef __bf16 bf16_t;
typedef bf16_t bf16x8 __attribute__((ext_vector_type(8)));
typedef bf16_t bf16x4 __attribute__((ext_vector_type(4)));
typedef float f32x4 __attribute__((ext_vector_type(4)));

// ---- f32 -> bf16 conversion (vectorized, total must be %4==0) ----
__global__ void k_conv4(const float* __restrict__ in, bf16_t* __restrict__ out, int total) {
    int idx = (blockIdx.x * blockDim.x + threadIdx.x) * 4;
    if (idx < total) {
        float4 v = *(const float4*)(in + idx);
        bf16x4 o;
        o[0] = (bf16_t)v.x; o[1] = (bf16_t)v.y; o[2] = (bf16_t)v.z; o[3] = (bf16_t)v.w;
        *(bf16x4*)(out + idx) = o;
    }
}

// ---- degree histogram ----
__global__ void k_hist(const int* __restrict__ col, int* __restrict__ deg, int E) {
    int e = blockIdx.x * blockDim.x + threadIdx.x;
    if (e < E) atomicAdd(deg + col[e], 1);
}

// ---- per-1024-chunk partial sums of deg ----
__global__ void k_partial(const int* __restrict__ deg, int* __restrict__ partial, int NN) {
    __shared__ int s[256];
    int base = blockIdx.x * 1024 + threadIdx.x * 4;
    int t = 0;
#pragma unroll
    for (int j = 0; j < 4; ++j) { int n = base + j; if (n < NN) t += deg[n]; }
    s[threadIdx.x] = t;
    __syncthreads();
    for (int off = 128; off > 0; off >>= 1) {
        if (threadIdx.x < off) s[threadIdx.x] += s[threadIdx.x + off];
        __syncthreads();
    }
    if (threadIdx.x == 0) partial[blockIdx.x] = s[0];
}

// ---- serial exclusive scan of the (tiny) partial array ----
__global__ void k_scan_partial(int* __restrict__ partial, int NB) {
    if (blockIdx.x == 0 && threadIdx.x == 0) {
        int run = 0;
        for (int i = 0; i < NB; ++i) { int t = partial[i]; partial[i] = run; run += t; }
    }
}

// ---- per-chunk exclusive scan -> CSC offsets, cursor copy, inv-degree ----
__global__ void k_offsets(const int* __restrict__ deg, const int* __restrict__ partial,
                          int* __restrict__ offs, int* __restrict__ cursor,
                          float* __restrict__ invdeg, int NN, int E) {
    __shared__ int s[256];
    int tid = threadIdx.x;
    int base = blockIdx.x * 1024 + tid * 4;
    int d[4]; int tsum = 0;
#pragma unroll
    for (int j = 0; j < 4; ++j) { int n = base + j; d[j] = (n < NN) ? deg[n] : 0; tsum += d[j]; }
    s[tid] = tsum;
    __syncthreads();
    for (int off = 1; off < 256; off <<= 1) {
        int v = (tid >= off) ? s[tid - off] : 0;
        __syncthreads();
        s[tid] += v;
        __syncthreads();
    }
    int run = partial[blockIdx.x] + s[tid] - tsum;  // exclusive base for this thread
#pragma unroll
    for (int j = 0; j < 4; ++j) {
        int n = base + j;
        if (n < NN) {
            offs[n] = run;
            cursor[n] = run;
            int dd = d[j] > 1 ? d[j] : 1;
            invdeg[n] = 1.0f / (float)dd;
            run += d[j];
        }
    }
    if (blockIdx.x == 0 && tid == 0) offs[NN] = E;
}

// ---- bucket edges by destination, one destination-RANGE per pass ----
// Restricting the active srcid window to ~0.8MB lets L2 accumulate all ~16
// writes to a node's 64B srcid segment before writeback (fixes the 105MB
// write-allocate blowup of the single-pass scatter).
__global__ void k_scatter_pass(const int* __restrict__ row, const int* __restrict__ col,
                               int* __restrict__ cursor, int* __restrict__ srcid,
                               int E, int lo, int hi) {
    int e = blockIdx.x * blockDim.x + threadIdx.x;
    if (e < E) {
        int c = col[e];
        if (c >= lo && c < hi) {
            int pos = atomicAdd(cursor + c, 1);
            srcid[pos] = row[e];
        }
    }
}

// ---- per-node segmented mean-aggregate (atomic-free), bf16 in/out ----
// One node per WAVE. Quarter-wave (16 lanes) per edge slot -> 4 edges
// gathered concurrently; each lane loads bf16x8 (16B). 4-edge unroll gives
// 4 independent gathers in flight per lane (one iteration covers the typical
// degree-16 node). Cross-quarter reduce via shfl_xor(16/32).
__global__ __launch_bounds__(256) void k_agg(const bf16_t* __restrict__ xbf, const int* __restrict__ offs,
                                             const int* __restrict__ srcid, const float* __restrict__ invdeg,
                                             bf16_t* __restrict__ msg, int NN) {
    const int wid  = threadIdx.x >> 6;
    const int lane = threadIdx.x & 63;
    const int n    = blockIdx.x * 4 + wid;
    if (n >= NN) return;
    const int qid = lane >> 4;     // edge slot 0..3
    const int f   = lane & 15;     // feature group: 8f .. 8f+7

    const int e0 = offs[n], e1 = offs[n + 1];

    float acc[8] = {0.f, 0.f, 0.f, 0.f, 0.f, 0.f, 0.f, 0.f};

    int e = e0 + qid;
    // 4-edge unrolled main loop: four independent row gathers in flight
    while (e + 12 < e1) {
        int s0 = srcid[e];
        int s1 = srcid[e + 4];
        int s2 = srcid[e + 8];
        int s3 = srcid[e + 12];
        bf16x8 v0 = *(const bf16x8*)(xbf + (size_t)s0 * H + f * 8);
        bf16x8 v1 = *(const bf16x8*)(xbf + (size_t)s1 * H + f * 8);
        bf16x8 v2 = *(const bf16x8*)(xbf + (size_t)s2 * H + f * 8);
        bf16x8 v3 = *(const bf16x8*)(xbf + (size_t)s3 * H + f * 8);
#pragma unroll
        for (int j = 0; j < 8; ++j)
            acc[j] += ((float)v0[j] + (float)v1[j]) + ((float)v2[j] + (float)v3[j]);
        e += 16;
    }
    while (e < e1) {
        int s0 = srcid[e];
        bf16x8 v0 = *(const bf16x8*)(xbf + (size_t)s0 * H + f * 8);
#pragma unroll
        for (int j = 0; j < 8; ++j) acc[j] += (float)v0[j];
        e += 4;
    }

    // reduce across the 4 quarter-waves (feature groups align across quarters)
#pragma unroll
    for (int j = 0; j < 8; ++j) {
        acc[j] += __shfl_xor(acc[j], 16);
        acc[j] += __shfl_xor(acc[j], 32);
    }

    if (qid == 0) {
        float inv = invdeg[n];
        bf16x8 o;
#pragma unroll
        for (int j = 0; j < 8; ++j) o[j] = (bf16_t)(acc[j] * inv);
        *(bf16x8*)(msg + (size_t)n * H + f * 8) = o;
    }
}

// ---- fused MFMA GEMM: out = xold + relu(msg @ W^T + bias); also refresh bf16 mirror ----
__global__ __launch_bounds__(256) void k_gemm(const bf16_t* __restrict__ msg, const bf16_t* __restrict__ wbf,
                                              const float* __restrict__ bias, const float* __restrict__ xold,
                                              float* __restrict__ xnew, bf16_t* __restrict__ xbf, int NN) {
    const int tid = threadIdx.x;
    const int wid = tid >> 6;          // wave 0..3
    const int lane = tid & 63;
    const int lr = lane & 15;          // A row / B col / D col
    const int lg = lane >> 4;          // k-group / D row-group
    const int m0 = blockIdx.x * 64 + wid * 16;   // wave's 16 output rows

    f32x4 acc[8] = {};
    int ar = m0 + lr;
    if (ar >= NN) ar = NN - 1;         // clamp: garbage rows only feed unstored outputs
    const bf16_t* arow = msg + (size_t)ar * H;

#pragma unroll
    for (int kk = 0; kk < 4; ++kk) {
        bf16x8 a = *(const bf16x8*)(arow + kk * 32 + lg * 8);
#pragma unroll
        for (int c = 0; c < 8; ++c) {
            bf16x8 b = *(const bf16x8*)(wbf + (size_t)(c * 16 + lr) * H + kk * 32 + lg * 8);
            acc[c] = __builtin_amdgcn_mfma_f32_16x16x32_bf16(a, b, acc[c], 0, 0, 0);
        }
    }

#pragma unroll
    for (int c = 0; c < 8; ++c) {
        int colN = c * 16 + lr;
        float bv = bias[colN];
#pragma unroll
        for (int j = 0; j < 4; ++j) {
            int r = m0 + lg * 4 + j;
            if (r < NN) {
                float v = acc[c][j] + bv;
                v = fmaxf(v, 0.f);
                size_t o = (size_t)r * H + colN;
                float xn = xold[o] + v;
                xnew[o] = xn;
                xbf[o] = (bf16_t)xn;
            }
        }
    }
}

extern "C" void kernel_launch(void* const* d_in, const int* in_sizes, int n_in,
                              void* d_out, int out_size, void* d_ws, size_t ws_size,
                              hipStream_t stream) {
    const float* x_in  = (const float*)d_in[0];
    const int*   erow  = (const int*)d_in[1];
    const float* W     = (const float*)d_in[2];
    const float* bias  = (const float*)d_in[3];

    const int NN = in_sizes[0] / H;      // 100000
    const int E  = in_sizes[1] / 2;      // 1600000
    const int* ecol = erow + E;

    float* xout = (float*)d_out;

    // workspace carve (256B aligned regions)
    char* p = (char*)d_ws;
    auto carve = [&](size_t bytes) -> char* {
        char* r = p;
        p += (bytes + 255) & ~(size_t)255;
        return r;
    };
    bf16_t* xbf    = (bf16_t*)carve((size_t)NN * H * 2);
    bf16_t* msg    = (bf16_t*)carve((size_t)NN * H * 2);
    bf16_t* wbf    = (bf16_t*)carve((size_t)H * H * 2);
    int*    deg    = (int*)carve((size_t)NN * 4);
    int*    offs   = (int*)carve((size_t)(NN + 1) * 4);
    int*    cursor = (int*)carve((size_t)NN * 4);
    float*  invdeg = (float*)carve((size_t)NN * 4);
    int*    srcid  = (int*)carve((size_t)E * 4);
    int*    partial= (int*)carve((size_t)((NN + 1023) / 1024) * 4);

    const int NB = (NN + 1023) / 1024;

    // ---- one-time setup per call ----
    k_conv4<<<(NN * H / 4 + 255) / 256, 256, 0, stream>>>(x_in, xbf, NN * H);
    k_conv4<<<(H * H / 4 + 255) / 256, 256, 0, stream>>>(W, wbf, H * H);
    hipMemsetAsync(deg, 0, (size_t)NN * 4, stream);
    k_hist<<<(E + 255) / 256, 256, 0, stream>>>(ecol, deg, E);
    k_partial<<<NB, 256, 0, stream>>>(deg, partial, NN);
    k_scan_partial<<<1, 64, 0, stream>>>(partial, NB);
    k_offsets<<<NB, 256, 0, stream>>>(deg, partial, offs, cursor, invdeg, NN, E);

    // binned scatter: 8 sequential destination-range passes for write locality
    const int NPASS = 8;
    const int step = (NN + NPASS - 1) / NPASS;
    for (int pass = 0; pass < NPASS; ++pass) {
        int lo = pass * step;
        int hi = (pass == NPASS - 1) ? NN : lo + step;
        k_scatter_pass<<<(E + 255) / 256, 256, 0, stream>>>(erow, ecol, cursor, srcid, E, lo, hi);
    }

    // ---- 6 message-passing iterations ----
    for (int it = 0; it < 6; ++it) {
        k_agg<<<(NN + 3) / 4, 256, 0, stream>>>(xbf, offs, srcid, invdeg, msg, NN);
        const float* xo = (it == 0) ? x_in : (const float*)xout;
        k_gemm<<<(NN + 63) / 64, 256, 0, stream>>>(msg, wbf, bias, xo, xout, xbf, NN);
    }
}